// Round 1
// baseline (92.777 us; speedup 1.0000x reference)
//
#include <hip/hip_runtime.h>

#define NPART 62
#define M     256
#define D     256
#define NPOS  8
#define NNEG  248
#define MARG  0.2f
#define BM    32          // anchors per block
#define BK    32          // k-slab
#define BPAD  36          // padded LDS row (floats), 144B: 16B-aligned rows, odd/4 stride -> conflict-free b128
#define REC   512         // ws record stride in floats per block
#define NBLK  (NPART*8)   // 496

#define OFF_HARD 15376    // 62*248
#define OFF_MD   15438
#define OFF_FN   15439

__global__ __launch_bounds__(256) void triplet_main(
    const float* __restrict__ F, const int* __restrict__ label, float* __restrict__ ws)
{
    // region holds Bt[256][BPAD] during GEMM (36864B), then distT[32][256] (32768B)
    __shared__ __align__(16) float region[256 * BPAD];
    __shared__ float x2s[M];
    __shared__ int   lab[M];
    __shared__ float posbuf[4][NPOS];
    __shared__ float fullS[4][NNEG];
    __shared__ float fullC[4][NNEG];
    __shared__ float wred[8];

    const int bx = blockIdx.x;
    const int p  = bx >> 3;
    const int ab = bx & 7;
    const int ib = ab * BM;
    const int t  = threadIdx.x;

    lab[t] = label[p * M + t];
    for (int idx = t; idx < 4 * NNEG; idx += 256) {
        (&fullS[0][0])[idx] = 0.f;
        (&fullC[0][0])[idx] = 0.f;
    }
    __syncthreads();

    const float4* Fv = (const float4*)(F + (size_t)p * (M * D));

    float acc[4][8];
#pragma unroll
    for (int r = 0; r < 4; ++r)
#pragma unroll
        for (int c = 0; c < 8; ++c) acc[r][c] = 0.f;

    float x2loc = 0.f;
    const int tc = t & 31;
    const int tg = t >> 5;

    for (int kt = 0; kt < D / BK; ++kt) {
        // stage Bt: all 256 rows x 32 k (2048 float4)
#pragma unroll
        for (int w = 0; w < 8; ++w) {
            int ch = w * 256 + t;
            int r  = ch >> 3;
            int q  = ch & 7;
            float4 v = Fv[r * (D / 4) + kt * 8 + q];
            float* dst = &region[r * BPAD + q * 4];
            dst[0] = v.x; dst[1] = v.y; dst[2] = v.z; dst[3] = v.w;
        }
        __syncthreads();
        // x^2 partial for row t
#pragma unroll
        for (int k4 = 0; k4 < 8; ++k4) {
            float4 b = *(const float4*)&region[t * BPAD + k4 * 4];
            x2loc += b.x * b.x + b.y * b.y + b.z * b.z + b.w * b.w;
        }
        // GEMM micro-tile 4x8
#pragma unroll
        for (int k4 = 0; k4 < 8; ++k4) {
            float4 a4[4], b4[8];
#pragma unroll
            for (int r = 0; r < 4; ++r)
                a4[r] = *(const float4*)&region[(ib + tg * 4 + r) * BPAD + k4 * 4];
#pragma unroll
            for (int c = 0; c < 8; ++c)
                b4[c] = *(const float4*)&region[(tc + 32 * c) * BPAD + k4 * 4];
#pragma unroll
            for (int r = 0; r < 4; ++r)
#pragma unroll
                for (int c = 0; c < 8; ++c)
                    acc[r][c] += a4[r].x * b4[c].x + a4[r].y * b4[c].y +
                                 a4[r].z * b4[c].z + a4[r].w * b4[c].w;
        }
        __syncthreads();
    }

    x2s[t] = x2loc;
    __syncthreads();

    // distances into region (overlays Bt; no one reads Bt anymore)
#pragma unroll
    for (int r = 0; r < 4; ++r) {
        int ii = tg * 4 + r;
        float xi = x2s[ib + ii];
#pragma unroll
        for (int c = 0; c < 8; ++c) {
            int j = tc + 32 * c;
            float d2 = xi + x2s[j] - 2.f * acc[r][c];
            region[ii * M + j] = sqrtf(fmaxf(d2, 0.f) + 1e-12f);
        }
    }
    __syncthreads();

    // ---- mining: wave w handles anchors ii = w*8 .. w*8+7 ----
    const int lane = t & 63;
    const int w    = t >> 6;
    const unsigned long long lmask = (1ull << lane) - 1ull;

    float hardAcc = 0.f;
    float rowSum  = 0.f;

    for (int a = 0; a < 8; ++a) {
        int ii = w * 8 + a;
        int li = lab[ib + ii];
        int runMatch = 0;
        float negmin = 3.4e38f;
        float ndv[4]; int nqv[4]; int nval[4];
#pragma unroll
        for (int ch = 0; ch < 4; ++ch) {
            int j = ch * 64 + lane;
            float d = region[ii * M + j];
            bool match = (lab[j] == li);
            unsigned long long bal = __ballot(match);
            int prefix  = __popcll(bal & lmask);
            int posRank = runMatch + prefix;
            if (match) {
                if (posRank < NPOS) posbuf[w][posRank] = d;
                nval[ch] = 0; ndv[ch] = 0.f; nqv[ch] = 0;
            } else {
                ndv[ch] = d; nqv[ch] = j - posRank; nval[ch] = 1;
                negmin = fminf(negmin, d);
            }
            runMatch += __popcll(bal);
            rowSum += d;
        }
        __syncthreads();  // uniform; guarantees posbuf writes land

        float maxpos = posbuf[w][0];
#pragma unroll
        for (int pp = 1; pp < NPOS; ++pp) maxpos = fmaxf(maxpos, posbuf[w][pp]);
#pragma unroll
        for (int off = 32; off >= 1; off >>= 1)
            negmin = fminf(negmin, __shfl_xor(negmin, off));
        hardAcc += fmaxf(MARG + maxpos - negmin, 0.f);

#pragma unroll
        for (int ch = 0; ch < 4; ++ch) {
            if (nval[ch]) {
                float dneg = ndv[ch]; int q = nqv[ch];
                float s = 0.f, cnt = 0.f;
#pragma unroll
                for (int pp = 0; pp < NPOS; ++pp) {
                    float v = MARG + posbuf[w][pp] - dneg;
                    if (v > 0.f) { s += v; cnt += 1.f; }
                }
                fullS[w][q] += s;   // distinct q per lane -> race-free
                fullC[w][q] += cnt;
            }
        }
        __syncthreads();
    }

    // block reductions -> ws partial record
#pragma unroll
    for (int off = 32; off >= 1; off >>= 1) rowSum += __shfl_xor(rowSum, off);
    if (lane == 0) { wred[w] = hardAcc; wred[4 + w] = rowSum; }
    __syncthreads();

    float* rec = ws + (size_t)bx * REC;
    if (t < NNEG) {
        float s = fullS[0][t] + fullS[1][t] + fullS[2][t] + fullS[3][t];
        float c = fullC[0][t] + fullC[1][t] + fullC[2][t] + fullC[3][t];
        rec[t] = s;
        rec[NNEG + t] = c;
    }
    if (t == 0) {
        rec[496] = wred[0] + wred[1] + wred[2] + wred[3];
        rec[497] = wred[4] + wred[5] + wred[6] + wred[7];
    }
}

__global__ __launch_bounds__(256) void triplet_finalize1(float* __restrict__ ws,
                                                         float* __restrict__ out)
{
    const int p = blockIdx.x;
    const int t = threadIdx.x;
    if (t < NNEG) {
        float s = 0.f, c = 0.f;
        for (int a = 0; a < 8; ++a) {
            const float* rec = ws + (size_t)(p * 8 + a) * REC;
            s += rec[t];
            c += rec[NNEG + t];
        }
        out[p * NNEG + t]          = s / (c + 1e-6f);
        out[OFF_FN + p * NNEG + t] = c;
    }
    if (t == 0) {
        float h = 0.f, ds = 0.f;
        for (int a = 0; a < 8; ++a) {
            const float* rec = ws + (size_t)(p * 8 + a) * REC;
            h  += rec[496];
            ds += rec[497];
        }
        out[OFF_HARD + p] = h * (1.0f / 256.0f);
        ws[(size_t)NBLK * REC + p] = ds;  // per-part dist sums
    }
}

__global__ void triplet_finalize2(const float* __restrict__ wsP, float* __restrict__ out)
{
    int t = threadIdx.x;
    float v = (t < NPART) ? wsP[t] : 0.f;
#pragma unroll
    for (int off = 32; off >= 1; off >>= 1) v += __shfl_xor(v, off);
    if (t == 0) out[OFF_MD] = v / (float)((size_t)NPART * M * M);
}

extern "C" void kernel_launch(void* const* d_in, const int* in_sizes, int n_in,
                              void* d_out, int out_size, void* d_ws, size_t ws_size,
                              hipStream_t stream)
{
    const float* F     = (const float*)d_in[0];
    const int*   label = (const int*)d_in[1];
    float*       ws    = (float*)d_ws;
    float*       out   = (float*)d_out;

    triplet_main<<<dim3(NBLK), dim3(256), 0, stream>>>(F, label, ws);
    triplet_finalize1<<<dim3(NPART), dim3(256), 0, stream>>>(ws, out);
    triplet_finalize2<<<dim3(1), dim3(64), 0, stream>>>(ws + (size_t)NBLK * REC, out);
}